// Round 12
// baseline (114.612 us; speedup 1.0000x reference)
//
#include <hip/hip_runtime.h>

// PopulationCoding, round 23.
//  r22 post-mortem: single-buffer k-loop serialization (-5us GEMM) canceled
//  the occupancy win; f16 LUT neutral (r20->r21). r19 counters: epi phase
//  VALUBusy ~50% because occupancy is GRID-limited (512 blk = 2/CU).
//  r23: keep r15's overlapped double-buffer k-loop (1 barrier/kt), fix
//  occupancy via grid shape: 32x64 tile, 1024 blocks = 4 blk/CU, 16
//  waves/CU. Epi = exactly 1 neuron/thread (half the serial chain of r15).
//  LDS 34KB: planes 2x12KB dbuf + Itile 32x65 + f16 nibble LUT. acc = 16
//  VGPR (vs 64) -> no spill.
// B=1024, IN=512, D=256, P=8, T=32. Output [1024,256] fp32.

constexpr int D_DIM   = 256;
constexpr int NTOT    = 2048;   // D*P
constexpr int T_STEPS = 32;

typedef _Float16 f16x8 __attribute__((ext_vector_type(8)));
typedef _Float16 half4 __attribute__((ext_vector_type(4)));
typedef float    f32x4 __attribute__((ext_vector_type(4)));
typedef ushort   ushort8 __attribute__((ext_vector_type(8)));

#define GLOBAL_AS __attribute__((address_space(1)))
#define LDS_AS    __attribute__((address_space(3)))

__device__ __forceinline__ void split_f16(float v, ushort& h, ushort& l) {
    const _Float16 hf = (_Float16)v;
    const _Float16 lf = (_Float16)((v - (float)hf) * 2048.0f);  // lo pre-scaled 2^11
    h = __builtin_bit_cast(ushort, hf);
    l = __builtin_bit_cast(ushort, lf);
}

// ------------------------------------------------- K0: split-f16 conversion
__device__ __forceinline__ void conv_x_body(const float* __restrict__ x,
                                            ushort* __restrict__ Ah,
                                            ushort* __restrict__ Al,
                                            int blk, int t)
{
    const int idx = (blk * 256 + t) * 8;
    float v[8];
    *reinterpret_cast<float4*>(v)     = *reinterpret_cast<const float4*>(x + idx);
    *reinterpret_cast<float4*>(v + 4) = *reinterpret_cast<const float4*>(x + idx + 4);
    __align__(16) ushort h[8], l[8];
#pragma unroll
    for (int j = 0; j < 8; ++j) split_f16(v[j], h[j], l[j]);
    *reinterpret_cast<ushort8*>(Ah + idx) = *reinterpret_cast<const ushort8*>(h);
    *reinterpret_cast<ushort8*>(Al + idx) = *reinterpret_cast<const ushort8*>(l);
}

__device__ __forceinline__ void conv_w_body(const float* __restrict__ Wp,
                                            ushort* __restrict__ Bh,
                                            ushort* __restrict__ Bl,
                                            float (*tile)[69],
                                            int ib, int t)
{
    const int k0 = (ib >> 5) * 64;          // 8 k-tiles
    const int c0 = (ib & 31) * 64;          // 32 col-tiles
    {
        const int r = t >> 2, cq = (t & 3) * 16;
#pragma unroll
        for (int j = 0; j < 4; ++j)
            *reinterpret_cast<float4*>(&tile[r][cq + j * 4]) =
                *reinterpret_cast<const float4*>(Wp + (size_t)(k0 + r) * NTOT + c0 + cq + j * 4);
    }
    __syncthreads();
    const int rr = t >> 2, kc2 = (t & 3) * 16;
    __align__(16) ushort h[16], l[16];
#pragma unroll
    for (int j = 0; j < 16; ++j) split_f16(tile[kc2 + j][rr], h[j], l[j]);
    ushort* dh = Bh + (size_t)(c0 + rr) * 512 + k0 + kc2;
    ushort* dl = Bl + (size_t)(c0 + rr) * 512 + k0 + kc2;
    *reinterpret_cast<ushort8*>(dh)     = *reinterpret_cast<const ushort8*>(h);
    *reinterpret_cast<ushort8*>(dh + 8) = *reinterpret_cast<const ushort8*>(h + 8);
    *reinterpret_cast<ushort8*>(dl)     = *reinterpret_cast<const ushort8*>(l);
    *reinterpret_cast<ushort8*>(dl + 8) = *reinterpret_cast<const ushort8*>(l + 8);
}

__global__ __launch_bounds__(256)
void popcode_prep(const float* __restrict__ x, const float* __restrict__ Wp,
                  ushort* __restrict__ Ah, ushort* __restrict__ Al,
                  ushort* __restrict__ Bh, ushort* __restrict__ Bl)
{
    __shared__ float tile[64][69];
    const int t = threadIdx.x;
    if (blockIdx.x < 256) conv_x_body(x, Ah, Al, blockIdx.x, t);
    else                  conv_w_body(Wp, Bh, Bl, tile, blockIdx.x - 256, t);
}

// ------------------------------------- K1: fused split-f16 MFMA GEMM + epi
// 1024 blocks (XCD-swizzled), 256 threads (4 waves). Tile 32x64, BK=32.
// LDS (34048 B, 4 blocks/CU):
//   [buf0 12288][buf1 12288][Itile 32x65 f32 = 8320][lut16 768][wlds 384]
//   per-buf planes: Ah 0 (2KB), Al 2048, Bh 4096 (4KB), Bl 8192 (4KB),
//   row-major [row][32 halves]; staging 64B contiguous per 4 lanes.
// Staging roles: w0=Ah(2 insts), w3=Al(2), w1=Bh(4), w2=Bl(4).
// Compute: wave w -> quadrant (wr=(w>>1)*16, wc=(w&1)*32), 1x2 frags.
__global__ __launch_bounds__(256)
void popcode_fused(const ushort* __restrict__ Ah_g, const ushort* __restrict__ Al_g,
                   const ushort* __restrict__ Bh_g, const ushort* __restrict__ Bl_g,
                   const float* __restrict__ bp, const float* __restrict__ thrs,
                   const float* __restrict__ rateW, const float* __restrict__ rateB,
                   const float* __restrict__ c1w, const float* __restrict__ c1b,
                   const float* __restrict__ c2w, const float* __restrict__ c2b,
                   const float* __restrict__ fus, float* __restrict__ out)
{
    __shared__ __align__(16) char smem[34048];
    LDS_AS char* lds0 = (LDS_AS char*)smem;

    const int tid  = threadIdx.x;
    const int w    = tid >> 6;
    const int lane = tid & 63;

    // bijective XCD swizzle: 1024 = 8 XCDs x 128 contiguous wgs.
    // 128 consecutive wgs = 4 N-tiles x 32 M-tiles -> A planes (2MB) + B
    // slice (0.5MB) L2-resident per XCD.
    const int wg = ((blockIdx.x & 7) << 7) | (blockIdx.x >> 3);
    const int b0 = (wg & 31) * 32;      // M tile (batch rows), 32 tiles
    const int c0 = (wg >> 5) * 64;      // N tile (neuron cols), 32 tiles

    // staging role per wave
    const ushort* gbase = (w == 0) ? Ah_g : (w == 3) ? Al_g : (w == 1) ? Bh_g : Bl_g;
    const bool    isA   = (w == 0) || (w == 3);
    const int     t0    = isA ? b0 : c0;
    const int     pbase = (w == 0) ? 0 : (w == 3) ? 2048 : (w == 1) ? 4096 : 8192;
    const int     srow  = lane >> 2;          // 4 lanes = 64B = one row
    const int     schk  = (lane & 3) * 8;     // 16B chunk, in halves

    const int wr = (w >> 1) * 16;       // quadrant row origin
    const int wc = (w & 1) * 32;        // quadrant col origin
    const int lr = lane & 15;
    const int lg = lane >> 4;

    const f32x4 zero = {0.f, 0.f, 0.f, 0.f};
    f32x4 acch[2] = {zero, zero};
    f32x4 accl[2] = {zero, zero};

    auto stage = [&](int buf, int kt) {
        const int koff = kt * 32 + schk;
        const int nb   = buf * 12288 + pbase;
#pragma unroll
        for (int i = 0; i < 2; ++i) {
            const ushort* src = gbase + (size_t)(t0 + srow + 16 * i) * 512 + koff;
            const int loff = __builtin_amdgcn_readfirstlane(nb + i * 1024);
            __builtin_amdgcn_global_load_lds((const GLOBAL_AS uint*)src,
                                             (LDS_AS uint*)(lds0 + loff), 16, 0, 0);
        }
        if (!isA) {
#pragma unroll
            for (int i = 2; i < 4; ++i) {
                const ushort* src = gbase + (size_t)(t0 + srow + 16 * i) * 512 + koff;
                const int loff = __builtin_amdgcn_readfirstlane(nb + i * 1024);
                __builtin_amdgcn_global_load_lds((const GLOBAL_AS uint*)src,
                                                 (LDS_AS uint*)(lds0 + loff), 16, 0, 0);
            }
        }
    };

    auto compute = [&](int buf) {
        const int nb = buf * 12288;
        f16x8 ah, al, bh[2], bl[2];
        {
            const int ro = (wr + lr) * 64 + lg * 16;
            ah = *reinterpret_cast<const f16x8*>(smem + nb +        ro);
            al = *reinterpret_cast<const f16x8*>(smem + nb + 2048 + ro);
        }
#pragma unroll
        for (int n = 0; n < 2; ++n) {
            const int co = (wc + n * 16 + lr) * 64 + lg * 16;
            bh[n] = *reinterpret_cast<const f16x8*>(smem + nb + 4096 + co);
            bl[n] = *reinterpret_cast<const f16x8*>(smem + nb + 8192 + co);
        }
#pragma unroll
        for (int n = 0; n < 2; ++n) {
            acch[n] = __builtin_amdgcn_mfma_f32_16x16x32_f16(ah, bh[n], acch[n], 0, 0, 0);
            accl[n] = __builtin_amdgcn_mfma_f32_16x16x32_f16(al, bh[n], accl[n], 0, 0, 0);
            accl[n] = __builtin_amdgcn_mfma_f32_16x16x32_f16(ah, bl[n], accl[n], 0, 0, 0);
        }
    };

    // ---- prologue: wlds, first stage; f16 LUT build overlaps load wait ----
    float* wlds  = (float*)(smem + 33664);
    half4* lut16 = (half4*)(smem + 32896);   // 96 entries x 8B
    if (tid < 96) wlds[tid] = c1w[tid];
    stage(0, 0);
    __syncthreads();                 // wlds visible; buf0 staged (vmcnt drained)

    if (tid < 96) {
        const int k = tid >> 5;          // tap 0..2
        const int j = (tid >> 4) & 1;    // p-half
        const int n = tid & 15;          // nibble
        half4 hv;
#pragma unroll
        for (int c = 0; c < 4; ++c) {
            float v = (k == 1 && j == 0) ? c1b[c] : 0.f;  // fold conv1 bias once
#pragma unroll
            for (int p = 0; p < 4; ++p)
                v = fmaf((float)((n >> p) & 1), wlds[(c * 8 + j * 4 + p) * 3 + k], v);
            hv[c] = (_Float16)v;
        }
        lut16[tid] = hv;                 // entry e = k*32 + j*16 + n
    }

    // ---- GEMM k-loop (double-buffered, 1 barrier/kt, r15 style) ----
    for (int kt = 0; kt < 16; ++kt) {
        if (kt < 15) stage((kt + 1) & 1, kt + 1);
        compute(kt & 1);
        __syncthreads();
    }

    // ---- acc -> Itile (C/D layout: col = lane&15, row = (lane>>4)*4 + v) ----
    float* it = (float*)(smem + 24576);  // [32][65]
    const float s = 1.0f / 2048.0f;
#pragma unroll
    for (int n = 0; n < 2; ++n)
#pragma unroll
        for (int v = 0; v < 4; ++v)
            it[(wr + lg * 4 + v) * 65 + wc + n * 16 + lr] =
                acch[n][v] + accl[n][v] * s;
    __syncthreads();

    // ---- uniform scalars ----
    float thrv[8];
#pragma unroll
    for (int p = 0; p < 8; ++p) thrv[p] = thrs[p];
    float w2c[4];
#pragma unroll
    for (int c = 0; c < 4; ++c) w2c[c] = c2w[c];
    const float f0 = fus[0], f1 = fus[1];
    const float fm = fmaxf(f0, f1);
    const float e0 = __expf(f0 - fm), e1 = __expf(f1 - fm);
    const float inv = 1.f / (e0 + e1);
    const float fw0 = e0 * inv, fw1 = e1 * inv;
    const float rb_ = rateB[0];
    const float bb2 = c2b[0];

    // ---- epilogue: exactly 1 neuron per thread (32 rows x 8 d) ----
    const int row  = tid >> 3;
    const int dloc = tid & 7;
    const int dg   = (c0 >> 3) + dloc;

    const float* ip = it + row * 65 + dloc * 8;
    float Iv[8], mem[8];
    bool  spk[8];
    {
        const float4 bv0 = *reinterpret_cast<const float4*>(bp + dg * 8);
        const float4 bv1 = *reinterpret_cast<const float4*>(bp + dg * 8 + 4);
        Iv[0] = ip[0] + bv0.x; Iv[1] = ip[1] + bv0.y;
        Iv[2] = ip[2] + bv0.z; Iv[3] = ip[3] + bv0.w;
        Iv[4] = ip[4] + bv1.x; Iv[5] = ip[5] + bv1.y;
        Iv[6] = ip[6] + bv1.z; Iv[7] = ip[7] + bv1.w;
    }
#pragma unroll
    for (int p = 0; p < 8; ++p) { mem[p] = 0.f; spk[p] = false; }

    // LIF, packing one byte per t (4 t per u32 word)
    unsigned wrd[8] = {0u, 0u, 0u, 0u, 0u, 0u, 0u, 0u};
#pragma unroll
    for (int t = 0; t < T_STEPS; ++t) {
        unsigned by = 0u;
#pragma unroll
        for (int p = 0; p < 8; ++p) {
            const float m2 = fmaf(0.95f, mem[p], Iv[p]);
            mem[p] = spk[p] ? (m2 - thrv[p]) : m2;
            spk[p] = mem[p] > thrv[p];
            by |= spk[p] ? (1u << p) : 0u;
        }
        wrd[t >> 2] |= by << (8 * (t & 3));
    }

    // rate branch: exact bit-plane popcount
    float rsum = 0.f;
#pragma unroll
    for (int p = 0; p < 8; ++p) {
        const unsigned m = 0x01010101u << p;
        int cnt = 0;
#pragma unroll
        for (int q = 0; q < 8; ++q) cnt += __popc(wrd[q] & m);
        rsum = fmaf((float)cnt, rateW[p], rsum);
    }

    // temporal conv: 6 conflict-free f16x4 nibble-LUT b64 reads per t
    auto getb = [&](int t) -> unsigned {
        return (wrd[t >> 2] >> (8 * (t & 3))) & 255u;
    };
    float tacc = 0.f;
    unsigned bp_ = 0u;
    unsigned bc_ = getb(0);
#pragma unroll
    for (int t = 0; t < T_STEPS; ++t) {
        const unsigned bn_ = (t < 31) ? getb(t + 1) : 0u;
        const half4 a0 = lut16[      (bp_ & 15)];
        const half4 a1 = lut16[16 + (bp_ >> 4)];
        const half4 b0 = lut16[32 + (bc_ & 15)];
        const half4 b1 = lut16[48 + (bc_ >> 4)];
        const half4 cv0 = lut16[64 + (bn_ & 15)];
        const half4 cv1 = lut16[80 + (bn_ >> 4)];
        const half4 hsum = (a0 + a1) + ((b0 + b1) + (cv0 + cv1));
        tacc = fmaf(fmaxf((float)hsum[0], 0.f), w2c[0], tacc);
        tacc = fmaf(fmaxf((float)hsum[1], 0.f), w2c[1], tacc);
        tacc = fmaf(fmaxf((float)hsum[2], 0.f), w2c[2], tacc);
        tacc = fmaf(fmaxf((float)hsum[3], 0.f), w2c[3], tacc);
        bp_ = bc_;
        bc_ = bn_;
    }

    const float rdec = rsum * (1.f / 32.f) + rb_;
    const float temp = tacc * (1.f / 32.f) + bb2;
    out[(b0 + row) * D_DIM + dg] = fw0 * rdec + fw1 * temp;
}

extern "C" void kernel_launch(void* const* d_in, const int* in_sizes, int n_in,
                              void* d_out, int out_size, void* d_ws, size_t ws_size,
                              hipStream_t stream) {
    const float* x     = (const float*)d_in[0];
    const float* Wp    = (const float*)d_in[1];
    const float* bp    = (const float*)d_in[2];
    const float* thrs  = (const float*)d_in[3];
    const float* rateW = (const float*)d_in[4];
    const float* rateB = (const float*)d_in[5];
    const float* c1w   = (const float*)d_in[6];
    const float* c1b   = (const float*)d_in[7];
    const float* c2w   = (const float*)d_in[8];
    const float* c2b   = (const float*)d_in[9];
    const float* fus   = (const float*)d_in[10];
    float* out = (float*)d_out;
    float* ws  = (float*)d_ws;

    // ws layout: Ah[1024*512]u16 | Al | Bh[2048*512]u16 | Bl   (12 MB)
    ushort* Ah = reinterpret_cast<ushort*>(ws);
    ushort* Al = Ah + 1024 * 512;
    ushort* Bh = Al + 1024 * 512;
    ushort* Bl = Bh + 2048 * 512;

    popcode_prep<<<dim3(512), dim3(256), 0, stream>>>(x, Wp, Ah, Al, Bh, Bl);
    popcode_fused<<<dim3(1024), dim3(256), 0, stream>>>(
        Ah, Al, Bh, Bl, bp, thrs, rateW, rateB, c1w, c1b, c2w, c2b, fus, out);
}

// Round 13
// 106.108 us; speedup vs baseline: 1.0801x; 1.0801x over previous
//
#include <hip/hip_runtime.h>

// PopulationCoding, round 24 — REVERT TO CHAMPION (r15 verbatim, 106.6us).
//  Ledger: r15=106.6 | r12=109.0 | r14=110.1 | r22=111.4 | r20=112.6 |
//  r21=113.8 | r23=114.6. Seven structural levers tried since r15 (tile
//  shape, grid/occupancy 2->4 blk/CU twice, single-buffer, frag-ordered
//  staging, byte/f16 LUTs, 1-neuron/thread, coop grid.sync) — ALL null or
//  regressions within/below the noise band. Occupancy model falsified
//  (r22+r23). Controllable time ~36us vs ~70us harness-fixed (1 fill @42us
//  80% HBM + ~28us dispatch slots). LIF recurrence serial-in-t floor +
//  LDS-pipe floor ~= the rest. Locking in the measured best.
// B=1024, IN=512, D=256, P=8, T=32. Output [1024,256] fp32.

constexpr int IN_DIM  = 512;
constexpr int D_DIM   = 256;
constexpr int NTOT    = 2048;   // D*P
constexpr int T_STEPS = 32;

typedef _Float16 f16x8 __attribute__((ext_vector_type(8)));
typedef float    f32x4 __attribute__((ext_vector_type(4)));
typedef ushort   ushort8 __attribute__((ext_vector_type(8)));

#define GLOBAL_AS __attribute__((address_space(1)))
#define LDS_AS    __attribute__((address_space(3)))

__device__ __forceinline__ void split_f16(float v, ushort& h, ushort& l) {
    const _Float16 hf = (_Float16)v;
    const _Float16 lf = (_Float16)((v - (float)hf) * 2048.0f);  // lo pre-scaled 2^11
    h = __builtin_bit_cast(ushort, hf);
    l = __builtin_bit_cast(ushort, lf);
}

// ------------------------------------------------- K0: split-f16 conversion
// blocks 0..255:   x [1024][512] -> Ah/Al [1024][512] (8 elems/thread)
// blocks 256..511: Wp [512][2048] -> Bh/Bl [2048][512] (64x64 LDS transpose,
//                  coalesced writes: thread t owns B-row t>>2, k-chunk t&3)
__global__ __launch_bounds__(256)
void popcode_prep(const float* __restrict__ x, const float* __restrict__ Wp,
                  ushort* __restrict__ Ah, ushort* __restrict__ Al,
                  ushort* __restrict__ Bh, ushort* __restrict__ Bl)
{
    __shared__ float tile[64][69];   // 69-pad: transpose reads <=2-way banked
    const int t = threadIdx.x;
    if (blockIdx.x < 256) {
        const int idx = (blockIdx.x * 256 + t) * 8;
        float v[8];
        *reinterpret_cast<float4*>(v)     = *reinterpret_cast<const float4*>(x + idx);
        *reinterpret_cast<float4*>(v + 4) = *reinterpret_cast<const float4*>(x + idx + 4);
        __align__(16) ushort h[8], l[8];
#pragma unroll
        for (int j = 0; j < 8; ++j) split_f16(v[j], h[j], l[j]);
        *reinterpret_cast<ushort8*>(Ah + idx) = *reinterpret_cast<const ushort8*>(h);
        *reinterpret_cast<ushort8*>(Al + idx) = *reinterpret_cast<const ushort8*>(l);
    } else {
        const int ib = blockIdx.x - 256;
        const int k0 = (ib >> 5) * 64;          // 8 k-tiles
        const int c0 = (ib & 31) * 64;          // 32 col-tiles
        {
            const int r = t >> 2, cq = (t & 3) * 16;
#pragma unroll
            for (int j = 0; j < 4; ++j)
                *reinterpret_cast<float4*>(&tile[r][cq + j * 4]) =
                    *reinterpret_cast<const float4*>(Wp + (size_t)(k0 + r) * NTOT + c0 + cq + j * 4);
        }
        __syncthreads();
        // thread t: B row rr = t>>2 (0..63), k-chunk kc2 = (t&3)*16
        const int rr = t >> 2, kc2 = (t & 3) * 16;
        __align__(16) ushort h[16], l[16];
#pragma unroll
        for (int j = 0; j < 16; ++j) split_f16(tile[kc2 + j][rr], h[j], l[j]);
        ushort* dh = Bh + (size_t)(c0 + rr) * 512 + k0 + kc2;
        ushort* dl = Bl + (size_t)(c0 + rr) * 512 + k0 + kc2;
        *reinterpret_cast<ushort8*>(dh)     = *reinterpret_cast<const ushort8*>(h);
        *reinterpret_cast<ushort8*>(dh + 8) = *reinterpret_cast<const ushort8*>(h + 8);
        *reinterpret_cast<ushort8*>(dl)     = *reinterpret_cast<const ushort8*>(l);
        *reinterpret_cast<ushort8*>(dl + 8) = *reinterpret_cast<const ushort8*>(l + 8);
    }
}

// ------------------------------------- K1: fused split-f16 MFMA GEMM + epi
// 512 blocks (XCD-swizzled), 256 threads (4 waves). Tile 64x64, BK=32.
// GEMM phase: wave w stages plane w, computes 32x32 quadrant.
// Then acc -> Itile (LDS, 65-pad) -> each thread runs 2 full neurons
// (8-chain LIF, popcount rate, full-32t nibble-LUT conv).
__global__ __launch_bounds__(256, 2)
void popcode_fused(const ushort* __restrict__ Ah_g, const ushort* __restrict__ Al_g,
                   const ushort* __restrict__ Bh_g, const ushort* __restrict__ Bl_g,
                   const float* __restrict__ bp,
                   const float* __restrict__ thrs,
                   const float* __restrict__ rateW,
                   const float* __restrict__ rateB,
                   const float* __restrict__ c1w,
                   const float* __restrict__ c1b,
                   const float* __restrict__ c2w,
                   const float* __restrict__ c2b,
                   const float* __restrict__ fus,
                   float* __restrict__ out)
{
    __shared__ __align__(16) ushort Lds[2][4][64][32];   // 32 KB staging
    __shared__ float Itile[64][65];                      // 16.6 KB, 65-pad
    __shared__ float lut[3][2][16][4];                   // 1.5 KB
    __shared__ float wlds[96];

    const int tid  = threadIdx.x;
    const int w    = tid >> 6;          // wave id = staged plane id
    const int lane = tid & 63;

    // bijective XCD swizzle: 512 = 8 XCDs x 64 contiguous wgs.
    const int wg = (blockIdx.x & 7) * 64 + (blockIdx.x >> 3);
    const int b0 = (wg & 15) * 64;      // M tile (batch rows)
    const int c0 = (wg >> 4) * 64;      // N tile (neuron cols)

    const ushort* gbase = (w == 0) ? Ah_g : (w == 1) ? Al_g : (w == 2) ? Bh_g : Bl_g;
    const int     t0    = (w < 2) ? b0 : c0;
    const int     srow  = lane >> 2;
    const int     schk  = (lane & 3) * 8;     // in halves

    const int wr = (w >> 1) * 32;       // quadrant row origin
    const int wc = (w & 1) * 32;        // quadrant col origin
    const int lr = lane & 15;
    const int lg = lane >> 4;           // k-group / output row group

    const f32x4 zero = {0.f, 0.f, 0.f, 0.f};
    f32x4 acch[2][2] = {{zero, zero}, {zero, zero}};
    f32x4 accl[2][2] = {{zero, zero}, {zero, zero}};

    LDS_AS char* lds0 = (LDS_AS char*)&Lds[0][0][0][0];

    auto stage = [&](int buf, int kt) {
        const int koff = kt * 32 + schk;
#pragma unroll
        for (int i = 0; i < 4; ++i) {
            const ushort* src = gbase + (size_t)(t0 + srow + 16 * i) * 512 + koff;
            const int loff = __builtin_amdgcn_readfirstlane(buf * 16384 + w * 4096 + i * 1024);
            __builtin_amdgcn_global_load_lds((const GLOBAL_AS uint*)src,
                                             (LDS_AS uint*)(lds0 + loff), 16, 0, 0);
        }
    };

    auto compute = [&](int buf) {
        f16x8 ah[2], al[2], bh[2], bl[2];
#pragma unroll
        for (int m = 0; m < 2; ++m) {
            const int row = wr + m * 16 + lr;
            ah[m] = *(const f16x8*)&Lds[buf][0][row][lg * 8];
            al[m] = *(const f16x8*)&Lds[buf][1][row][lg * 8];
        }
#pragma unroll
        for (int n = 0; n < 2; ++n) {
            const int col = wc + n * 16 + lr;
            bh[n] = *(const f16x8*)&Lds[buf][2][col][lg * 8];
            bl[n] = *(const f16x8*)&Lds[buf][3][col][lg * 8];
        }
#pragma unroll
        for (int m = 0; m < 2; ++m)
#pragma unroll
            for (int n = 0; n < 2; ++n) {
                acch[m][n] = __builtin_amdgcn_mfma_f32_16x16x32_f16(ah[m], bh[n], acch[m][n], 0, 0, 0);
                accl[m][n] = __builtin_amdgcn_mfma_f32_16x16x32_f16(al[m], bh[n], accl[m][n], 0, 0, 0);
                accl[m][n] = __builtin_amdgcn_mfma_f32_16x16x32_f16(ah[m], bl[n], accl[m][n], 0, 0, 0);
            }
    };

    // ---- prologue: wlds + first stage; LUT build overlaps load latency ----
    if (tid < 96) wlds[tid] = c1w[tid];
    stage(0, 0);
    __syncthreads();                 // wlds visible; buf0 staged (vmcnt drained)

    for (int e = tid; e < 384; e += 256) {
        const int k  = e >> 7;           // tap 0..2
        const int j  = (e >> 6) & 1;     // p-half
        const int nb = (e >> 2) & 15;    // nibble
        const int c  = e & 3;            // channel
        float v = (k == 1 && j == 0) ? c1b[c] : 0.f;  // fold conv1 bias once
#pragma unroll
        for (int p = 0; p < 4; ++p)
            v = fmaf((float)((nb >> p) & 1), wlds[(c * 8 + j * 4 + p) * 3 + k], v);
        (&lut[0][0][0][0])[e] = v;
    }

    // ---- GEMM k-loop ----
    for (int kt = 0; kt < 16; ++kt) {
        if (kt < 15) stage((kt + 1) & 1, kt + 1);
        compute(kt & 1);
        __syncthreads();
    }

    // ---- acc -> Itile (C/D layout: col = lane&15, row = (lane>>4)*4 + v) ----
    const float s = 1.0f / 2048.0f;
#pragma unroll
    for (int m = 0; m < 2; ++m)
#pragma unroll
        for (int n = 0; n < 2; ++n)
#pragma unroll
            for (int v = 0; v < 4; ++v)
                Itile[wr + m * 16 + lg * 4 + v][wc + n * 16 + lr] =
                    acch[m][n][v] + accl[m][n][v] * s;
    __syncthreads();

    // ---- uniform scalars ----
    float w2c[4];
#pragma unroll
    for (int c = 0; c < 4; ++c) w2c[c] = c2w[c];
    float rW[8], thrv[8];
#pragma unroll
    for (int p = 0; p < 8; ++p) { rW[p] = rateW[p]; thrv[p] = thrs[p]; }
    const float rb_ = rateB[0];
    const float bb2 = c2b[0];
    const float f0 = fus[0], f1 = fus[1];
    const float fm = fmaxf(f0, f1);
    const float e0 = __expf(f0 - fm), e1 = __expf(f1 - fm);
    const float inv = 1.f / (e0 + e1);
    const float fw0 = e0 * inv, fw1 = e1 * inv;

    const float* lutf = &lut[0][0][0][0];

    // ---- epilogue: 2 full neurons per thread ----
    for (int half = 0; half < 2; ++half) {
        const int nb   = tid + half * 256;   // 0..511
        const int row  = nb >> 3;            // batch-local 0..63
        const int dloc = nb & 7;
        const int dg   = (c0 >> 3) + dloc;   // global d

        const float* ip = &Itile[row][dloc * 8];
        const float4 bv0 = *reinterpret_cast<const float4*>(bp + dg * 8);
        const float4 bv1 = *reinterpret_cast<const float4*>(bp + dg * 8 + 4);
        const float bpx[8] = {bv0.x, bv0.y, bv0.z, bv0.w, bv1.x, bv1.y, bv1.z, bv1.w};

        float Iv[8], Imt[8], mem[8];
        bool  spk[8];
#pragma unroll
        for (int p = 0; p < 8; ++p) {
            Iv[p]  = ip[p] + bpx[p];
            Imt[p] = Iv[p] - thrv[p];
            mem[p] = 0.f;
            spk[p] = false;
        }

        unsigned nibL[4] = {0u, 0u, 0u, 0u}, nibH[4] = {0u, 0u, 0u, 0u};
#pragma unroll
        for (int t = 0; t < T_STEPS; ++t) {
            unsigned bl_ = 0u, bh_ = 0u;
#pragma unroll
            for (int p = 0; p < 8; ++p) {
                mem[p] = 0.95f * mem[p] + (spk[p] ? Imt[p] : Iv[p]);
                spk[p] = mem[p] > thrv[p];
            }
#pragma unroll
            for (int p = 0; p < 4; ++p) bl_ |= spk[p] ? (1u << p) : 0u;
#pragma unroll
            for (int p = 4; p < 8; ++p) bh_ |= spk[p] ? (1u << (p - 4)) : 0u;
            nibL[t >> 3] |= bl_ << (4 * (t & 7));
            nibH[t >> 3] |= bh_ << (4 * (t & 7));
        }

        // rate: exact bit-plane popcount
        float rsum = 0.f;
#pragma unroll
        for (int p = 0; p < 4; ++p) {
            const unsigned m = 0x11111111u << p;
            const int cL = __popc(nibL[0] & m) + __popc(nibL[1] & m)
                         + __popc(nibL[2] & m) + __popc(nibL[3] & m);
            const int cH = __popc(nibH[0] & m) + __popc(nibH[1] & m)
                         + __popc(nibH[2] & m) + __popc(nibH[3] & m);
            rsum = fmaf((float)cL, rW[p], rsum);
            rsum = fmaf((float)cH, rW[4 + p], rsum);
        }

        // conv: full 32-t range, 6 nibble-LUT reads per t
        auto getn = [](const unsigned* a, int t) -> unsigned {
            return (a[t >> 3] >> (4 * (t & 7))) & 15u;
        };
        float tacc = 0.f;
        unsigned nlp = 0u, nhp = 0u;
        unsigned nlc = getn(nibL, 0), nhc = getn(nibH, 0);
#pragma unroll
        for (int t = 0; t < T_STEPS; ++t) {
            const unsigned nln = (t < 31) ? getn(nibL, t + 1) : 0u;
            const unsigned nhn = (t < 31) ? getn(nibH, t + 1) : 0u;
            const float4 a0 = *reinterpret_cast<const float4*>(lutf + (nlp     ) * 4);
            const float4 a1 = *reinterpret_cast<const float4*>(lutf + (nhp + 16) * 4);
            const float4 b0 = *reinterpret_cast<const float4*>(lutf + (nlc + 32) * 4);
            const float4 b1 = *reinterpret_cast<const float4*>(lutf + (nhc + 48) * 4);
            const float4 c0v = *reinterpret_cast<const float4*>(lutf + (nln + 64) * 4);
            const float4 c1v = *reinterpret_cast<const float4*>(lutf + (nhn + 80) * 4);
            const float h0_ = ((a0.x + a1.x) + (b0.x + b1.x)) + (c0v.x + c1v.x);
            const float h1_ = ((a0.y + a1.y) + (b0.y + b1.y)) + (c0v.y + c1v.y);
            const float h2_ = ((a0.z + a1.z) + (b0.z + b1.z)) + (c0v.z + c1v.z);
            const float h3_ = ((a0.w + a1.w) + (b0.w + b1.w)) + (c0v.w + c1v.w);
            tacc = fmaf(fmaxf(h0_, 0.f), w2c[0], tacc);
            tacc = fmaf(fmaxf(h1_, 0.f), w2c[1], tacc);
            tacc = fmaf(fmaxf(h2_, 0.f), w2c[2], tacc);
            tacc = fmaf(fmaxf(h3_, 0.f), w2c[3], tacc);
            nlp = nlc; nhp = nhc; nlc = nln; nhc = nhn;
        }

        const float rdec = rsum * (1.f / 32.f) + rb_;
        const float temp = tacc * (1.f / 32.f) + bb2;
        out[(b0 + row) * D_DIM + dg] = fw0 * rdec + fw1 * temp;
    }
}

extern "C" void kernel_launch(void* const* d_in, const int* in_sizes, int n_in,
                              void* d_out, int out_size, void* d_ws, size_t ws_size,
                              hipStream_t stream) {
    const float* x     = (const float*)d_in[0];
    const float* Wp    = (const float*)d_in[1];
    const float* bp    = (const float*)d_in[2];
    const float* thrs  = (const float*)d_in[3];
    const float* rateW = (const float*)d_in[4];
    const float* rateB = (const float*)d_in[5];
    const float* c1w   = (const float*)d_in[6];
    const float* c1b   = (const float*)d_in[7];
    const float* c2w   = (const float*)d_in[8];
    const float* c2b   = (const float*)d_in[9];
    const float* fus   = (const float*)d_in[10];
    float* out = (float*)d_out;
    float* ws  = (float*)d_ws;

    // ws layout: Ah[1024*512]u16 | Al | Bh[2048*512]u16 | Bl   (12 MB)
    ushort* Ah = reinterpret_cast<ushort*>(ws);
    ushort* Al = Ah + 1024 * 512;
    ushort* Bh = Al + 1024 * 512;
    ushort* Bl = Bh + 2048 * 512;

    popcode_prep<<<dim3(512), dim3(256), 0, stream>>>(x, Wp, Ah, Al, Bh, Bl);
    popcode_fused<<<dim3(512), dim3(256), 0, stream>>>(
        Ah, Al, Bh, Bl, bp, thrs, rateW, rateB, c1w, c1b, c2w, c2b, fus, out);
}